// Round 5
// baseline (463.650 us; speedup 1.0000x reference)
//
#include <hip/hip_runtime.h>
#include <math.h>

#define NB    16        // batch
#define NC    25        // channels
#define HW    65536     // 256*256
#define CHW   (NC * HW)
#define EPSF  1e-8f
#define TPB   320       // 5 waves: wave w owns channels 5w..5w+4
#define PXB   256       // pixels per block
#define NBLK  (NB * (HW / PXB))   // 16 * 256 = 4096 blocks

union F4 { float4 v; float a[4]; };

__device__ __forceinline__ float wave_reduce(float v) {
#pragma unroll
    for (int o = 32; o > 0; o >>= 1) v += __shfl_down(v, o, 64);
    return v;
}

// R12: channel-parallel waves, memcpy-shaped streaming.
// R11's decisive fact: dur is IDENTICAL whether HBM supplies 105MB or 0.2MB
// (L3-warm dispatches at same 169us) -> the wall was never bandwidth; it's
// the lockstep burst->vmcnt(0)-drain pattern (every XCD's blocks issue
// tsunamis together, drain together, consume on an empty pipe). Inter-block
// MLP gave exactly zero (R11 = R7 instr counts, half the rate).
// Fix: eliminate staging/barr..drain entirely. 5-wave blocks; wave w owns
// channels 5w..5w+4 for the block's 256 px -> each wave = 10 independent
// float4 loads (whole working set, nothing to pipeline), like memcpy.
// Wave 0: BCE+F1+size/offset (ch0-4). Waves 1-4: partial argmax of labels
// carrying outputs -> (max,out) per px into 8KB of ordinary LDS (ds_write,
// no global_load_lds aliasing drain) -> ONE barrier -> wave 0 combines in
// ascending group order (strict '>' = first-index tie-break), computes cls,
// reduces, atomics. ~20 waves/CU slipping freely vs R7's 4.
__global__ __launch_bounds__(TPB) void yolo_main(const float* __restrict__ outputs,
                                                 const float* __restrict__ labels,
                                                 float* __restrict__ acc,
                                                 unsigned* __restrict__ ticket,
                                                 float* __restrict__ out) {
    __shared__ float pm[4][PXB];      // partial max  (waves 1..4)
    __shared__ float po[4][PXB];      // out at max
    __shared__ float fin[4 + 3 * NB];
    __shared__ unsigned oldt;

    const int w    = threadIdx.x >> 6;        // wave id 0..4 (uniform)
    const int lane = threadIdx.x & 63;
    const int b    = blockIdx.x >> 8;         // image
    const int pxb  = (blockIdx.x & 255) << 8; // first pixel of block
    const size_t chbase = ((size_t)b * NC + 5 * w) * HW + pxb + lane * 4;
    const float* op = outputs + chbase;       // this wave's ch group, 4 px/lane
    const float* lp = labels  + chbase;

    // ---- 10 independent float4 loads: the wave's entire working set
    F4 o[5], l[5];
#pragma unroll
    for (int k = 0; k < 5; ++k) {
        o[k].v = *(const float4*)(op + (size_t)k * HW);
        l[k].v = *(const float4*)(lp + (size_t)k * HW);
    }

    float obj = 0.f, szs = 0.f, offs = 0.f, cls = 0.f;
    float tp = 0.f, fp = 0.f, fn = 0.f;
    float y0[4];

    if (w == 0) {
        // ---- channels 0..4: BCE + F1 + size/offset L1
#pragma unroll
        for (int i = 0; i < 4; ++i) {
            float xv = o[0].a[i], yv = l[0].a[i];
            float xc = fminf(fmaxf(xv,        EPSF), 1.0f - EPSF);
            float x1 = fminf(fmaxf(1.0f - xv, EPSF), 1.0f - EPSF);
            obj += -yv * (1.0f - xc) * __logf(xc)
                   - (1.0f - yv) * (1.0f - x1) * __logf(x1);
            float p  = (xv > 0.5f) ? 1.f : 0.f;
            float yt = (yv > 0.5f) ? 1.f : 0.f;
            tp += p * yt;
            fp += p * (1.f - yt);
            fn += (1.f - p) * yt;
            y0[i] = yv;
        }
#pragma unroll
        for (int k = 1; k <= 4; ++k) {
            float s = 0.f;
#pragma unroll
            for (int i = 0; i < 4; ++i) s += y0[i] * fabsf(o[k].a[i] - l[k].a[i]);
            if (k <= 2) szs += s; else offs += s;
        }
    } else {
        // ---- partial argmax over this wave's 5 channels (ascending k,
        //      strict '>' = first-index tie-break within the group)
        float vmax[4], vout[4];
#pragma unroll
        for (int i = 0; i < 4; ++i) { vmax[i] = -1.0f; vout[i] = 0.0f; }
#pragma unroll
        for (int k = 0; k < 5; ++k) {
#pragma unroll
            for (int i = 0; i < 4; ++i) {
                if (l[k].a[i] > vmax[i]) { vmax[i] = l[k].a[i]; vout[i] = o[k].a[i]; }
            }
        }
#pragma unroll
        for (int i = 0; i < 4; ++i) {
            pm[w - 1][lane * 4 + i] = vmax[i];
            po[w - 1][lane * 4 + i] = vout[i];
        }
    }
    __syncthreads();                          // partials visible to wave 0

    if (w == 0) {
        // ---- combine 4 group partials in ascending group order
#pragma unroll
        for (int i = 0; i < 4; ++i) {
            const int px = lane * 4 + i;
            float vmax = -1.0f, vout = 0.0f;
#pragma unroll
            for (int g = 0; g < 4; ++g) {
                float m = pm[g][px];
                if (m > vmax) { vmax = m; vout = po[g][px]; }
            }
            cls += y0[i] * (-vout);
        }

        // ---- wave reduction (all 7 values live only in wave 0)
        obj  = wave_reduce(obj);
        szs  = wave_reduce(szs);
        offs = wave_reduce(offs);
        cls  = wave_reduce(cls);
        tp   = wave_reduce(tp);
        fp   = wave_reduce(fp);
        fn   = wave_reduce(fn);

        if (lane == 0) {
            atomicAdd(&acc[0], obj);
            atomicAdd(&acc[1], szs);
            atomicAdd(&acc[2], offs);
            atomicAdd(&acc[3], cls);
            atomicAdd(&acc[4 + 3 * b], tp);
            atomicAdd(&acc[5 + 3 * b], fp);
            atomicAdd(&acc[6 + 3 * b], fn);
        }
    }
    __syncthreads();                          // atomics issued before ticket

    // ---- ticket: last block finalizes (replaces yolo_fin launch)
    if (threadIdx.x == 0) {
        __threadfence();                      // release acc adds (same thread)
        oldt = atomicAdd(ticket, 1u);
    }
    __syncthreads();
    if (oldt == NBLK - 1) {
        if (threadIdx.x < 4 + 3 * NB) {
            // coherent RMW-read: sees every block's released adds
            fin[threadIdx.x] = atomicAdd(&acc[threadIdx.x], 0.0f);
        }
        __syncthreads();
        if (threadIdx.x == 0) {
            float objT = fin[0];
            float szT  = 0.1f * fin[1];
            float offT = 0.1f * fin[2];
            float clsT = fin[3];
            float f1 = 0.f;
            for (int bb = 0; bb < NB; ++bb) {
                float tpv = fin[4 + 3 * bb], fpv = fin[5 + 3 * bb], fnv = fin[6 + 3 * bb];
                float den = 2.f * tpv + fpv + fnv;
                f1 += (den > 0.f) ? (2.f * tpv) / fmaxf(den, 1.f) : 0.f;
            }
            f1 *= (1.0f / NB);
            out[0] = objT + szT + offT + clsT;
            out[1] = f1;
            out[2] = objT;
            out[3] = szT;
            out[4] = offT;
            out[5] = clsT;
        }
    }
}

extern "C" void kernel_launch(void* const* d_in, const int* in_sizes, int n_in,
                              void* d_out, int out_size, void* d_ws, size_t ws_size,
                              hipStream_t stream) {
    const float* outputs = (const float*)d_in[0];
    const float* labels  = (const float*)d_in[1];
    float* acc = (float*)d_ws;                    // [0..3] losses, [4+3b..] tp,fp,fn
    unsigned* ticket = (unsigned*)((float*)d_ws + 4 + 3 * NB);

    hipMemsetAsync(d_ws, 0, (4 + 3 * NB + 1) * sizeof(float), stream);
    yolo_main<<<NBLK, TPB, 0, stream>>>(outputs, labels, acc, ticket, (float*)d_out);
}

// Round 6
// 221.285 us; speedup vs baseline: 2.0953x; 2.0953x over previous
//
#include <hip/hip_runtime.h>
#include <math.h>

#define NB    16        // batch
#define NC    25        // channels
#define HW    65536     // 256*256
#define CHW   (NC * HW)
#define EPSF  1e-8f
#define TPB   320       // 5 waves: wave w owns channels 5w..5w+4
#define PXB   256       // pixels per block
#define NBLK  (NB * (HW / PXB))   // 4096 blocks
#define NSTR  64        // accumulator stripes (parallel atomic chains)
#define SACC  64        // floats per stripe (52 used, padded to 64 = 4 lines)

union F4 { float4 v; float a[4]; };

__device__ __forceinline__ float wave_reduce(float v) {
#pragma unroll
    for (int o = 32; o > 0; o >>= 1) v += __shfl_down(v, o, 64);
    return v;
}

// R13: break the atomic RMW chain. Evidence across R7/R11/R12: duration =
// ~78ns x NBLK regardless of memory structure (75/169/318us at 1024/2048/
// 4096 blocks), and L3-warm dispatches run EXACTLY as long as cold ones ->
// the kernel was serialized on the atomicAdd chain to the single cache
// line holding acc[0..3] (one TCC slice processes ~20ns/RMW; 4 RMW/block).
// Fix: 64 striped accumulator copies (block uses stripe bid&63) -> 64
// parallel chains of 256 RMW (~5us, hidden); separate 1-wave fin kernel
// reduces the stripes (the ticket was itself a 4096-RMW single-address
// chain; a graph-captured extra launch measured ~free in R8->R9).
// Memory structure stays R12's channel-parallel streaming (never actually
// measured un-throttled) + sched_barrier(0) after the 10-load bundle
// (R12's VGPR=32 proved the loads were sunk to serial; 40 live regs here,
// far from R10's 2x40+fences spill regime) + float4 LDS partial writes
// (R12's 666K bank conflicts were the lane*4 scalar stores).
__global__ __launch_bounds__(TPB) void yolo_main(const float* __restrict__ outputs,
                                                 const float* __restrict__ labels,
                                                 float* __restrict__ acc) {
    __shared__ F4 pm[4][64];      // per-group argmax partial: max
    __shared__ F4 po[4][64];      // per-group argmax partial: out@max

    const int w    = threadIdx.x >> 6;        // wave id 0..4 (uniform)
    const int lane = threadIdx.x & 63;
    const int b    = blockIdx.x >> 8;         // image
    const int pxb  = (blockIdx.x & 255) << 8; // first pixel of block
    const size_t chbase = ((size_t)b * NC + 5 * w) * HW + pxb + lane * 4;
    const float* op = outputs + chbase;       // this wave's ch group, 4 px/lane
    const float* lp = labels  + chbase;

    // ---- 10 independent float4 loads: the wave's entire working set.
    F4 o[5], l[5];
#pragma unroll
    for (int k = 0; k < 5; ++k) {
        o[k].v = *(const float4*)(op + (size_t)k * HW);
        l[k].v = *(const float4*)(lp + (size_t)k * HW);
    }
    // fence: loads may not sink below this point -> 10 outstanding per wave
    __builtin_amdgcn_sched_barrier(0);

    float obj = 0.f, szs = 0.f, offs = 0.f, cls = 0.f;
    float tp = 0.f, fp = 0.f, fn = 0.f;
    float y0[4];

    if (w == 0) {
        // ---- channels 0..4: BCE + F1 + size/offset L1
#pragma unroll
        for (int i = 0; i < 4; ++i) {
            float xv = o[0].a[i], yv = l[0].a[i];
            float xc = fminf(fmaxf(xv,        EPSF), 1.0f - EPSF);
            float x1 = fminf(fmaxf(1.0f - xv, EPSF), 1.0f - EPSF);
            obj += -yv * (1.0f - xc) * __logf(xc)
                   - (1.0f - yv) * (1.0f - x1) * __logf(x1);
            float p  = (xv > 0.5f) ? 1.f : 0.f;
            float yt = (yv > 0.5f) ? 1.f : 0.f;
            tp += p * yt;
            fp += p * (1.f - yt);
            fn += (1.f - p) * yt;
            y0[i] = yv;
        }
#pragma unroll
        for (int k = 1; k <= 4; ++k) {
            float s = 0.f;
#pragma unroll
            for (int i = 0; i < 4; ++i) s += y0[i] * fabsf(o[k].a[i] - l[k].a[i]);
            if (k <= 2) szs += s; else offs += s;
        }
    } else {
        // ---- partial argmax over this wave's 5 channels (ascending k,
        //      strict '>' = first-index tie-break within the group)
        F4 vmax, vout;
#pragma unroll
        for (int i = 0; i < 4; ++i) { vmax.a[i] = -1.0f; vout.a[i] = 0.0f; }
#pragma unroll
        for (int k = 0; k < 5; ++k) {
#pragma unroll
            for (int i = 0; i < 4; ++i) {
                if (l[k].a[i] > vmax.a[i]) { vmax.a[i] = l[k].a[i]; vout.a[i] = o[k].a[i]; }
            }
        }
        pm[w - 1][lane] = vmax;   // ds_write_b128, conflict-free
        po[w - 1][lane] = vout;
    }
    __syncthreads();                          // partials visible to wave 0

    if (w == 0) {
        // ---- combine 4 group partials in ascending group order
        float vmax[4], vout[4];
#pragma unroll
        for (int i = 0; i < 4; ++i) { vmax[i] = -1.0f; vout[i] = 0.0f; }
#pragma unroll
        for (int g = 0; g < 4; ++g) {
            F4 m = pm[g][lane];               // ds_read_b128
            F4 q = po[g][lane];
#pragma unroll
            for (int i = 0; i < 4; ++i) {
                if (m.a[i] > vmax[i]) { vmax[i] = m.a[i]; vout[i] = q.a[i]; }
            }
        }
#pragma unroll
        for (int i = 0; i < 4; ++i) cls += y0[i] * (-vout[i]);

        // ---- wave reduction (all 7 values live only in wave 0)
        obj  = wave_reduce(obj);
        szs  = wave_reduce(szs);
        offs = wave_reduce(offs);
        cls  = wave_reduce(cls);
        tp   = wave_reduce(tp);
        fp   = wave_reduce(fp);
        fn   = wave_reduce(fn);

        if (lane == 0) {
            // striped accumulators: 64 parallel short chains instead of one
            // 16384-RMW chain on a single line
            float* s = acc + (size_t)(blockIdx.x & (NSTR - 1)) * SACC;
            atomicAdd(s + 0, obj);
            atomicAdd(s + 1, szs);
            atomicAdd(s + 2, offs);
            atomicAdd(s + 3, cls);
            atomicAdd(s + 4 + 3 * b + 0, tp);
            atomicAdd(s + 4 + 3 * b + 1, fp);
            atomicAdd(s + 4 + 3 * b + 2, fn);
        }
    }
}

__global__ void yolo_fin(const float* __restrict__ acc, float* __restrict__ out) {
    const int t = threadIdx.x;                // 64 threads, 1 wave
    __shared__ float fin[52];
    if (t < 52) {
        float s = 0.f;
#pragma unroll
        for (int st = 0; st < NSTR; ++st) s += acc[st * SACC + t];
        fin[t] = s;
    }
    __syncthreads();
    if (t == 0) {
        float objT = fin[0];
        float szT  = 0.1f * fin[1];
        float offT = 0.1f * fin[2];
        float clsT = fin[3];
        float f1 = 0.f;
        for (int bb = 0; bb < NB; ++bb) {
            float tpv = fin[4 + 3 * bb], fpv = fin[5 + 3 * bb], fnv = fin[6 + 3 * bb];
            float den = 2.f * tpv + fpv + fnv;
            f1 += (den > 0.f) ? (2.f * tpv) / fmaxf(den, 1.f) : 0.f;
        }
        f1 *= (1.0f / NB);
        out[0] = objT + szT + offT + clsT;
        out[1] = f1;
        out[2] = objT;
        out[3] = szT;
        out[4] = offT;
        out[5] = clsT;
    }
}

extern "C" void kernel_launch(void* const* d_in, const int* in_sizes, int n_in,
                              void* d_out, int out_size, void* d_ws, size_t ws_size,
                              hipStream_t stream) {
    const float* outputs = (const float*)d_in[0];
    const float* labels  = (const float*)d_in[1];
    float* acc = (float*)d_ws;   // 64 stripes x 64 floats = 16 KB

    hipMemsetAsync(acc, 0, NSTR * SACC * sizeof(float), stream);
    yolo_main<<<NBLK, TPB, 0, stream>>>(outputs, labels, acc);
    yolo_fin<<<1, 64, 0, stream>>>(acc, (float*)d_out);
}